// Round 1
// 147.304 us; speedup vs baseline: 1.1113x; 1.1113x over previous
//
#include <hip/hip_runtime.h>
#include <hip/hip_bf16.h>

#define NN 4096
#define NFEAT 512
#define NHID 64
#define NHEAD 8
#define NCLASS 16
#define CAP 192
#define LALPHA 0.2f

#define SZ2 (NHEAD*2*NHID)   // a_heads
#define SZ3 (NHEAD*NHID)     // b_heads
#define SZ4 (NFEAT*NCLASS)   // W_out
#define SZ5 (2*NCLASS)       // a_out
#define SZ6 (NCLASS)         // b_out
#define NSMALL (SZ2+SZ3+SZ4+SZ5+SZ6)
#define NZERO (NN*NN/32 + NN + NHEAD*NHID + NCLASS)

typedef __attribute__((ext_vector_type(8))) short bf16x8;
typedef __attribute__((ext_vector_type(4))) float f32x4;
typedef __attribute__((ext_vector_type(8))) unsigned short u16x8;

// ---------- helpers ----------
__device__ __forceinline__ float b2f(unsigned short h) {
    return __uint_as_float(((unsigned int)h) << 16);
}
__device__ __forceinline__ unsigned short f2b(float f) {
    unsigned int u = __float_as_uint(f);
    unsigned int r = (u + 0x7fffu + ((u >> 16) & 1u)) >> 16;
    return (unsigned short)r;
}
__device__ __forceinline__ float waveMax(float v) {
#pragma unroll
    for (int m = 32; m >= 1; m >>= 1) v = fmaxf(v, __shfl_xor(v, m, 64));
    return v;
}
__device__ __forceinline__ float waveSum(float v) {
#pragma unroll
    for (int m = 32; m >= 1; m >>= 1) v += __shfl_xor(v, m, 64);
    return v;
}
__device__ __forceinline__ float lrelu(float e) {
    return e >= 0.f ? e : LALPHA * e;
}

// ---------- prep: W-transpose + edge-bitmap OR + feature/small casts ----------
__global__ void __launch_bounds__(256)
k_prep(const void* __restrict__ f, const void* __restrict__ Wh_,
       const void* __restrict__ ah_, const void* __restrict__ bh_,
       const void* __restrict__ Wo_, const void* __restrict__ ao_,
       const void* __restrict__ bo_, const int* __restrict__ e32,
       int E, int csb,
       unsigned short* __restrict__ featb,
       unsigned short* __restrict__ Wtb,
       float* __restrict__ smallf,
       unsigned int* __restrict__ bits) {
    __shared__ int sbf;
    int t = threadIdx.x;
    if (t < 64) {
        unsigned int w = ((const unsigned int*)f)[t];
        unsigned int lo = w & 0xffffu, e = (lo >> 7) & 0xffu;
        unsigned long long bal = __ballot(lo == 0u || (e >= 100u && e <= 140u));
        if (t == 0) sbf = (__popcll(bal) >= 40);
    }
    __syncthreads();
    bool bf = (sbf != 0);
    if (blockIdx.x < 128) {
        __shared__ float tile[64][33];
        int h = blockIdx.x >> 4, k0 = (blockIdx.x & 15) * 32;
        int n = t & 63, kh = t >> 6;
#pragma unroll
        for (int i = 0; i < 8; ++i) {
            int kk = kh * 8 + i;
            int si = (h << 15) + (k0 + kk) * NHID + n;
            float v = bf ? b2f(((const unsigned short*)Wh_)[si])
                         : ((const float*)Wh_)[si];
            tile[n][kk] = v;
        }
        __syncthreads();
        int n2 = t >> 2, kk0 = (t & 3) * 8;
        u16x8 o;
#pragma unroll
        for (int i = 0; i < 8; ++i) o[i] = f2b(tile[n2][kk0 + i]);
        *(u16x8*)&Wtb[(size_t)((h << 6) + n2) * NFEAT + k0 + kk0] = o;
    } else if ((int)blockIdx.x < 128 + csb) {
        // fire-and-forget bitmap OR (no return value -> no atomic round-trip wait)
        __shared__ int s64f;
        if (t < 64) {
            unsigned long long bal = __ballot(e32[2 * t + 1] == 0);
            if (t == 0) s64f = (__popcll(bal) >= 48);
        }
        __syncthreads();
        int i = (blockIdx.x - 128) * 256 + t;
        if (i < E) {
            int s, tt;
            if (s64f) { s = e32[2 * i]; tt = e32[2 * (E + i)]; }
            else      { s = e32[i];     tt = e32[E + i]; }
            s &= (NN - 1); tt &= (NN - 1);
            unsigned int pos = (unsigned int)s * NN + (unsigned int)tt;
            atomicOr(&bits[pos >> 5], 1u << (pos & 31u));
        }
    } else {
        const int NF8 = NN * NFEAT / 8;
        int i = (blockIdx.x - 128 - csb) * 256 + t;
        int stride = (gridDim.x - 128 - csb) * 256;
        const int TOT = NF8 + NSMALL;
        for (; i < TOT; i += stride) {
            if (i < NF8) {
                if (bf) {
                    *(u16x8*)&featb[i * 8] = ((const u16x8*)f)[i];
                } else {
                    float4 lo = ((const float4*)f)[i * 2];
                    float4 hi = ((const float4*)f)[i * 2 + 1];
                    u16x8 o;
                    o[0] = f2b(lo.x); o[1] = f2b(lo.y); o[2] = f2b(lo.z); o[3] = f2b(lo.w);
                    o[4] = f2b(hi.x); o[5] = f2b(hi.y); o[6] = f2b(hi.z); o[7] = f2b(hi.w);
                    *(u16x8*)&featb[i * 8] = o;
                }
            } else {
                int r = i - NF8;
                const void* sp; int off;
                if (r < SZ2)                        { sp = ah_; off = r; }
                else if (r < SZ2 + SZ3)             { sp = bh_; off = r - SZ2; }
                else if (r < SZ2 + SZ3 + SZ4)       { sp = Wo_; off = r - SZ2 - SZ3; }
                else if (r < SZ2 + SZ3 + SZ4 + SZ5) { sp = ao_; off = r - SZ2 - SZ3 - SZ4; }
                else                                { sp = bo_; off = r - SZ2 - SZ3 - SZ4 - SZ5; }
                smallf[r] = bf ? b2f(((const unsigned short*)sp)[off])
                               : ((const float*)sp)[off];
            }
        }
    }
}

// ---------- merged: MFMA gemm1 (blocks [0,256)) + bitmap extract (blocks [256,1280)) ----------
// H output is NODE-MAJOR: Hb[n][h*64+col] so layer-1 gather is one 1KB coalesced load/neighbor.
__global__ void __launch_bounds__(256)
k_gemm_ext(const unsigned short* __restrict__ Ab,   // [NN][NFEAT] bf16
           const unsigned short* __restrict__ Wtb,  // [NHEAD][NHID][NFEAT] bf16
           const float* __restrict__ ah,            // [NHEAD][2*NHID]
           unsigned short* __restrict__ Hb,         // [NN][NHEAD*NHID] bf16
           float* __restrict__ s1, float* __restrict__ s2,   // [NHEAD][NN]
           float* __restrict__ cm1,                 // [NHEAD][NHID]
           const unsigned int* __restrict__ bits,
           int* __restrict__ deg, int* __restrict__ csr) {
    int t = threadIdx.x;
    if (blockIdx.x >= 256) {
        // ---- extract: bitmap row -> sorted CSR row + deg (no atomics) ----
        int wid = t >> 6, lane = t & 63;
        int n = (blockIdx.x - 256) * 4 + wid;
        uint2 w = *(const uint2*)&bits[n * 128 + lane * 2];
        int c = __popc(w.x) + __popc(w.y);
        int incl = c;
#pragma unroll
        for (int off = 1; off < 64; off <<= 1) {
            int u = __shfl_up(incl, off, 64);
            if (lane >= off) incl += u;
        }
        int excl = incl - c;
        int total = __shfl(incl, 63, 64);
        if (lane == 0) deg[n] = total;
        int base = n * CAP;
        int tbase = lane * 64;
        unsigned int x = w.x;
        while (x) {
            int b = __ffs(x) - 1; x &= x - 1;
            if (excl < CAP) csr[base + excl] = tbase + b;
            ++excl;
        }
        unsigned int y = w.y;
        while (y) {
            int b = __ffs(y) - 1; y &= y - 1;
            if (excl < CAP) csr[base + excl] = tbase + 32 + b;
            ++excl;
        }
        return;
    }
    // ---- gemm1: b in [0,256), h = b>>5, bx = b&31 ----
    __shared__ float cms[64];
    if (t < 64) cms[t] = 0.f;
    __syncthreads();
    int w = t >> 6, l = t & 63;
    int quad = l >> 4, l16 = l & 15;
    int h = blockIdx.x >> 5;
    int m0 = (blockIdx.x & 31) * 128 + w * 32;
    f32x4 acc[2][4] = {};
    const unsigned short* a0p = Ab + (size_t)(m0 + l16) * NFEAT + quad * 8;
    const unsigned short* a1p = a0p + 16 * NFEAT;
    const unsigned short* bp  = Wtb + ((size_t)h << 15) + (size_t)l16 * NFEAT + quad * 8;
#pragma unroll 4
    for (int k0 = 0; k0 < NFEAT; k0 += 32) {
        bf16x8 a0 = *(const bf16x8*)(a0p + k0);
        bf16x8 a1 = *(const bf16x8*)(a1p + k0);
#pragma unroll
        for (int nt = 0; nt < 4; ++nt) {
            bf16x8 b = *(const bf16x8*)(bp + (size_t)nt * 16 * NFEAT + k0);
            acc[0][nt] = __builtin_amdgcn_mfma_f32_16x16x32_bf16(a0, b, acc[0][nt], 0, 0, 0);
            acc[1][nt] = __builtin_amdgcn_mfma_f32_16x16x32_bf16(a1, b, acc[1][nt], 0, 0, 0);
        }
    }
    const float* av = ah + h * 2 * NHID;
    float p1[2][4] = {}, p2[2][4] = {};
#pragma unroll
    for (int rh = 0; rh < 2; ++rh) {
#pragma unroll
        for (int nt = 0; nt < 4; ++nt) {
            int col = nt * 16 + l16;
            float av1 = av[col], av2 = av[NHID + col];
            float csum = 0.f;
#pragma unroll
            for (int r = 0; r < 4; ++r) {
                float v = acc[rh][nt][r];
                int row = m0 + rh * 16 + quad * 4 + r;
                Hb[((size_t)row << 9) + (h << 6) + col] = f2b(v);   // node-major
                p1[rh][r] += v * av1;
                p2[rh][r] += v * av2;
                csum += v;
            }
            atomicAdd(&cms[col], csum);
        }
    }
#pragma unroll
    for (int m = 8; m >= 1; m >>= 1)
#pragma unroll
        for (int rh = 0; rh < 2; ++rh)
#pragma unroll
            for (int r = 0; r < 4; ++r) {
                p1[rh][r] += __shfl_xor(p1[rh][r], m, 64);
                p2[rh][r] += __shfl_xor(p2[rh][r], m, 64);
            }
    if (l16 == 0) {
#pragma unroll
        for (int rh = 0; rh < 2; ++rh)
#pragma unroll
            for (int r = 0; r < 4; ++r) {
                int row = m0 + rh * 16 + quad * 4 + r;
                s1[(h << 12) + row] = p1[rh][r];
                s2[(h << 12) + row] = p2[rh][r];
            }
    }
    __syncthreads();
    if (t < 64) atomicAdd(&cm1[h * NHID + t], cms[t]);
}

// ---------- fused layer-1: all-head softmax + SpMM + bias + ELU + gemm2 + scores2 + colmean2 ----------
// One wave per NODE. lane l owns X columns [8l,8l+8): head h=l>>3. Gather is one
// coalesced 1KB load per neighbor; accumulator needs NO cross-lane reduction; the
// full X row stays in the wave -> the 512x16 GEMM + scores fuse in (k_gemm2f gone).
__global__ void __launch_bounds__(256)
k_attn1f(const int* __restrict__ deg, const int* __restrict__ csr,
         const float* __restrict__ s1, const float* __restrict__ s2,
         const unsigned short* __restrict__ Hb,   // [NN][NHEAD*NHID] bf16
         const float* __restrict__ bh, const float* __restrict__ cm1,
         const float* __restrict__ Wo, const float* __restrict__ ao,
         float* __restrict__ out2, float* __restrict__ s1o,
         float* __restrict__ s2o, float* __restrict__ cm2) {
    __shared__ float sW[4][CAP * 8];   // per-wave: weight[j][h] (e then w, in-place)
    __shared__ int   sT[4][CAP];       // per-wave: neighbor ids
    __shared__ float xr[4][NFEAT];     // per-wave: post-ELU X row
    __shared__ float cms[NCLASS];
    int t = threadIdx.x;
    if (t < NCLASS) cms[t] = 0.f;
    __syncthreads();
    int wid = t >> 6, lane = t & 63;
    int n = blockIdx.x * 4 + wid;
    int h = lane >> 3, jslot = lane & 7;
    int d = min(deg[n], CAP);
    float acc[8] = {};
    float rden = 1.f;
    if (d > 0) {
        const int* row = csr + (size_t)n * CAP;
        const float* s2h = s2 + ((size_t)h << 12);
        float s1n = s1[(h << 12) + n];
        // pass 1: raw scores for 8 heads x 8 neighbor-slots per iter; track max
        float mx = -1e30f;
        for (int jb = 0; jb < d; jb += 8) {
            int j = jb + jslot;
            int tt = (j < d) ? (row[j] & (NN - 1)) : 0;
            float e = (j < d) ? lrelu(s1n + s2h[tt]) : -1e30f;
            sW[wid][(j << 3) + h] = e;          // 64 consecutive words: conflict-free
            if (h == 0) sT[wid][j] = tt;
            mx = fmaxf(mx, e);
        }
        // per-head max: lanes sharing h differ only in bits 0..2
        mx = fmaxf(mx, __shfl_xor(mx, 1, 64));
        mx = fmaxf(mx, __shfl_xor(mx, 2, 64));
        mx = fmaxf(mx, __shfl_xor(mx, 4, 64));
        // pass 2: w = exp(e-m), accumulate denominator
        float den = 0.f;
        for (int jb = 0; jb < d; jb += 8) {
            int j = jb + jslot;
            float e = sW[wid][(j << 3) + h];
            float w = __expf(e - mx);           // pads: exp(-inf) = 0
            sW[wid][(j << 3) + h] = w;
            den += w;
        }
        den += __shfl_xor(den, 1, 64);
        den += __shfl_xor(den, 2, 64);
        den += __shfl_xor(den, 4, 64);
        rden = 1.f / den;
        // gather: one 1KB coalesced load per neighbor, weight broadcast from LDS
        const unsigned short* Hp = Hb + lane * 8;
        int j = 0;
#pragma unroll 2
        for (; j + 2 <= d; j += 2) {
            int t0 = sT[wid][j], t1 = sT[wid][j + 1];
            float w0 = sW[wid][(j << 3) + h];
            float w1 = sW[wid][((j + 1) << 3) + h];
            u16x8 v0 = *(const u16x8*)(Hp + ((size_t)t0 << 9));
            u16x8 v1 = *(const u16x8*)(Hp + ((size_t)t1 << 9));
#pragma unroll
            for (int i = 0; i < 8; ++i)
                acc[i] += w0 * b2f(v0[i]) + w1 * b2f(v1[i]);
        }
        if (j < d) {
            int t0 = sT[wid][j];
            float w0 = sW[wid][(j << 3) + h];
            u16x8 v0 = *(const u16x8*)(Hp + ((size_t)t0 << 9));
#pragma unroll
            for (int i = 0; i < 8; ++i) acc[i] += w0 * b2f(v0[i]);
        }
    }
    // normalize (or uniform-row colmean), bias, ELU -> X row in registers
    float o[8];
    if (d == 0) {
#pragma unroll
        for (int i = 0; i < 8; ++i) o[i] = cm1[lane * 8 + i] * (1.0f / NN);
    } else {
#pragma unroll
        for (int i = 0; i < 8; ++i) o[i] = acc[i] * rden;
    }
#pragma unroll
    for (int i = 0; i < 8; ++i) {
        float v = o[i] + bh[lane * 8 + i];
        o[i] = v > 0.f ? v : __expf(v) - 1.f;   // ELU
    }
    *(float4*)&xr[wid][lane * 8]     = make_float4(o[0], o[1], o[2], o[3]);
    *(float4*)&xr[wid][lane * 8 + 4] = make_float4(o[4], o[5], o[6], o[7]);
    // fused gemm2: out2[n][c] = X[n] . Wo[:,c]  (xr broadcast reads are free)
    int c = lane & 15, sub = lane >> 4;
    const float* xp = &xr[wid][sub * 128];
    const float* wp = Wo + sub * 128 * NCLASS + c;
    float a2 = 0.f;
#pragma unroll 8
    for (int kk = 0; kk < 128; ++kk) a2 += xp[kk] * wp[kk * NCLASS];
    a2 += __shfl_xor(a2, 16, 64);
    a2 += __shfl_xor(a2, 32, 64);
    if (lane < 16) out2[n * NCLASS + c] = a2;
    float r1 = a2 * ao[c], r2 = a2 * ao[NCLASS + c];
#pragma unroll
    for (int m = 8; m >= 1; m >>= 1) {
        r1 += __shfl_xor(r1, m, 16);
        r2 += __shfl_xor(r2, m, 16);
    }
    if (lane == 0) { s1o[n] = r1; s2o[n] = r2; }
    if (lane < 16) atomicAdd(&cms[c], a2);
    __syncthreads();
    if (t < NCLASS) atomicAdd(&cm2[t], cms[t]);
}

// ---------- layer-2: softmax + SpMM + bias + log_softmax ----------
__global__ void __launch_bounds__(256)
k_attn2(const int* __restrict__ deg, const int* __restrict__ csr,
        const float* __restrict__ s1o, const float* __restrict__ s2o,
        const float* __restrict__ out2, const float* __restrict__ bo,
        const float* __restrict__ cm2, float* __restrict__ outp) {
    __shared__ float2 wts[4][CAP];
    __shared__ float o2s[4][16];
    int wid = threadIdx.x >> 6, lane = threadIdx.x & 63;
    int n = blockIdx.x * 4 + wid;
    int c = lane & 15;
    int d = min(deg[n], CAP);
    float val;
    if (d == 0) {
        val = cm2[c] * (1.0f / NN);
    } else {
        float s1n = s1o[n];
        const int* row = csr + (size_t)n * CAP;
        int t0 = (lane < d)       ? (row[lane]       & (NN - 1)) : 0;
        int t1 = (lane + 64 < d)  ? (row[lane + 64]  & (NN - 1)) : 0;
        int t2 = (lane + 128 < d) ? (row[lane + 128] & (NN - 1)) : 0;
        float e0 = (lane < d)       ? lrelu(s1n + s2o[t0]) : -1e30f;
        float e1 = (lane + 64 < d)  ? lrelu(s1n + s2o[t1]) : -1e30f;
        float e2 = (lane + 128 < d) ? lrelu(s1n + s2o[t2]) : -1e30f;
        float m = waveMax(fmaxf(e0, fmaxf(e1, e2)));
        float w0 = (lane < d)       ? __expf(e0 - m) : 0.f;
        float w1 = (lane + 64 < d)  ? __expf(e1 - m) : 0.f;
        float w2 = (lane + 128 < d) ? __expf(e2 - m) : 0.f;
        float den = waveSum(w0 + w1 + w2);
        wts[wid][lane]       = make_float2(w0, __int_as_float(t0 << 4));
        wts[wid][lane + 64]  = make_float2(w1, __int_as_float(t1 << 4));
        wts[wid][lane + 128] = make_float2(w2, __int_as_float(t2 << 4));
        int g2 = lane >> 2, q = lane & 3;
        float a4[4] = {};
        for (int j = g2; j < d; j += 16) {
            float2 p = wts[wid][j];
            float4 v = *(const float4*)(out2 + __float_as_int(p.y) + q * 4);
            a4[0] += p.x * v.x; a4[1] += p.x * v.y;
            a4[2] += p.x * v.z; a4[3] += p.x * v.w;
        }
#pragma unroll
        for (int m2 = 4; m2 <= 32; m2 <<= 1)
#pragma unroll
            for (int i = 0; i < 4; ++i) a4[i] += __shfl_xor(a4[i], m2, 64);
        if (lane < 4)
            *(float4*)&o2s[wid][lane * 4] = make_float4(a4[0], a4[1], a4[2], a4[3]);
        val = o2s[wid][c] / den;
    }
    val += bo[c];
    float mx = val;
#pragma unroll
    for (int m = 8; m >= 1; m >>= 1) mx = fmaxf(mx, __shfl_xor(mx, m, 16));
    float se = __expf(val - mx);
#pragma unroll
    for (int m = 8; m >= 1; m >>= 1) se += __shfl_xor(se, m, 16);
    float res = val - mx - __logf(se);
    if (lane < 16) outp[n * NCLASS + lane] = res;
}

extern "C" void kernel_launch(void* const* d_in, const int* in_sizes, int n_in,
                              void* d_out, int out_size, void* d_ws, size_t ws_size,
                              hipStream_t stream) {
    const void* features = d_in[0];
    const int*  edges    = (const int*)d_in[1];
    const void* W_heads  = d_in[2];
    const void* a_heads  = d_in[3];
    const void* b_heads  = d_in[4];
    const void* W_out    = d_in[5];
    const void* a_out    = d_in[6];
    const void* b_out    = d_in[7];
    int E = in_sizes[1] / 2;

    // ---- workspace layout (4B units) ----
    unsigned int* bits = (unsigned int*)d_ws;                  // NN*NN/32
    int*   deg  = (int*)(bits + (NN * NN / 32));               // NN
    float* cm1  = (float*)(deg + NN);                          // NHEAD*NHID
    float* cm2  = cm1 + NHEAD * NHID;                          // NCLASS (zero region end)
    int*   csr  = (int*)(cm2 + NCLASS);                        // NN*CAP
    float* s1   = (float*)(csr + NN * CAP);                    // NHEAD*NN
    float* s2   = s1 + NHEAD * NN;                             // NHEAD*NN
    float* out2 = s2 + NHEAD * NN;                             // NN*NCLASS
    float* s1o  = out2 + NN * NCLASS;                          // NN
    float* s2o  = s1o + NN;                                    // NN
    unsigned short* Hb    = (unsigned short*)(s2o + NN);       // NN*NHEAD*NHID bf16 (node-major)
    unsigned short* featb = Hb + (size_t)NHEAD * NN * NHID;    // NN*NFEAT bf16
    unsigned short* Wtb   = featb + (size_t)NN * NFEAT;        // NHEAD*NHID*NFEAT bf16
    float* smallf = (float*)(Wtb + NHEAD * NHID * NFEAT);      // NSMALL fp32
    float* ahf = smallf;
    float* bhf = ahf + SZ2;
    float* Wof = bhf + SZ3;
    float* aof = Wof + SZ4;
    float* bof = aof + SZ5;
    float* outp = (float*)d_out;

    int csb = (E + 255) / 256;
    hipMemsetAsync(d_ws, 0, (size_t)NZERO * 4, stream);        // bits+deg+cm1+cm2
    hipLaunchKernelGGL(k_prep, dim3(128 + csb + 896), dim3(256), 0, stream,
                       features, W_heads, a_heads, b_heads, W_out, a_out, b_out,
                       edges, E, csb, featb, Wtb, smallf, bits);
    hipLaunchKernelGGL(k_gemm_ext, dim3(256 + NN / 4), dim3(256), 0, stream,
                       featb, Wtb, ahf, Hb, s1, s2, cm1, bits, deg, csr);
    hipLaunchKernelGGL(k_attn1f, dim3(NN / 4), dim3(256), 0, stream,
                       deg, csr, s1, s2, Hb, bhf, cm1, Wof, aof, out2, s1o, s2o, cm2);
    hipLaunchKernelGGL(k_attn2, dim3(NN / 4), dim3(256), 0, stream,
                       deg, csr, s1o, s2o, out2, bof, cm2, outp);
}